// Round 16
// baseline (9393.272 us; speedup 1.0000x reference)
//
#include <hip/hip_runtime.h>
#include <hip/hip_fp16.h>
#include <cstdint>
#include <cstddef>

#define N_E 2048
#define N_I 512
#define N_TOT 2560
#define BATCH 64
#define TSTEPS 512
#define INDIM 128
#define GD 16                 // gather batch depth (one round-trip for ns<=16)
#define ROWB 1280             // compressed row stride: 320B bitmap + 160B cum + 800B values

typedef float f32x4 __attribute__((ext_vector_type(4)));

// ------------------------------------------------------------------
// Dense signed-relu weight table Wd[pre][post] (fp16), tiled transpose.
// (source for the compressed table; not read by the sim)
// ------------------------------------------------------------------
#define TS 64
__global__ __launch_bounds__(256) void build_wd_kernel(
    const float* __restrict__ Wee, const float* __restrict__ Wie,
    const float* __restrict__ Wei, const float* __restrict__ Wii,
    __half* __restrict__ Wd)
{
    __shared__ float tile[TS][TS + 1];
    int P0 = blockIdx.x * TS;   // pre base
    int Q0 = blockIdx.y * TS;   // post base
    int tx = threadIdx.x & 63, ty = threadIdx.x >> 6;

    const float* W; int ldw, po_off, pr_off; float sign;
    bool preE = (P0 < N_E), postE = (Q0 < N_E);
    if (postE && preE)        { W = Wee; ldw = N_E; po_off = 0;   pr_off = 0;   sign =  1.f; }
    else if (!postE && preE)  { W = Wie; ldw = N_E; po_off = N_E; pr_off = 0;   sign =  1.f; }
    else if (postE && !preE)  { W = Wei; ldw = N_I; po_off = 0;   pr_off = N_E; sign = -1.f; }
    else                      { W = Wii; ldw = N_I; po_off = N_E; pr_off = N_E; sign = -1.f; }

    for (int r = ty; r < TS; r += 4) {
        int post = Q0 + r, pre = P0 + tx;
        float v = W[(size_t)(post - po_off) * ldw + (pre - pr_off)];
        tile[r][tx] = (v > 0.f) ? sign * v : 0.f;
    }
    __syncthreads();
    for (int r = ty; r < TS; r += 4) {
        int pre = P0 + r, post = Q0 + tx;
        Wd[(size_t)pre * N_TOT + post] = __float2half(tile[tx][r]);
    }
}

// ------------------------------------------------------------------
// Compress each Wd row: bitmap u32[80] | cum u16[80] | values fp16[<=400]
// bit set iff stored half is nonzero; values packed post-ascending.
// ------------------------------------------------------------------
__global__ __launch_bounds__(128) void compress_kernel(
    const __half* __restrict__ Wd, char* __restrict__ sp)
{
    __shared__ unsigned short cnt_s[80];
    __shared__ unsigned short cum_s[80];
    int j = blockIdx.x, t = threadIdx.x;
    const unsigned short* row = (const unsigned short*)(Wd + (size_t)j * N_TOT);
    unsigned mask = 0;
    if (t < 80) {
        int cnt = 0;
        for (int b = 0; b < 32; ++b) {
            unsigned short h = row[t * 32 + b];
            if (h & 0x7FFF) { mask |= (1u << b); ++cnt; }
        }
        cnt_s[t] = (unsigned short)cnt;
    }
    __syncthreads();
    if (t == 0) {
        unsigned a = 0;
        for (int w = 0; w < 80; ++w) { cum_s[w] = (unsigned short)a; a += cnt_s[w]; }
    }
    __syncthreads();
    char* rb = sp + (size_t)j * ROWB;
    if (t < 80) {
        ((unsigned*)rb)[t] = mask;
        ((unsigned short*)(rb + 320))[t] = cum_s[t];
        unsigned short* vals = (unsigned short*)(rb + 480);
        int o = cum_s[t];
        for (int b = 0; b < 32; ++b)
            if ((mask >> b) & 1u) { if (o < 400) vals[o] = row[t * 32 + b]; ++o; }
    }
}

// ------------------------------------------------------------------
// Input projection GEMM (nt store of the single-use stream).
// ------------------------------------------------------------------
#define PBM 128
#define PBN 64
#define PBK 32
__global__ __launch_bounds__(256) void proj_kernel(
    const float* __restrict__ x, const float* __restrict__ We, const float* __restrict__ Wi,
    float* __restrict__ out, int t0)
{
    __shared__ __align__(16) float As[PBK][132];
    __shared__ __align__(16) float Bs[PBK][68];
    int tid = threadIdx.x;
    int bx = blockIdx.x, by = blockIdx.y;
    int tx = tid & 15, ty = tid >> 4;
    float acc[8][4];
#pragma unroll
    for (int i = 0; i < 8; ++i)
#pragma unroll
        for (int j = 0; j < 4; ++j) acc[i][j] = 0.0f;

    for (int kb = 0; kb < INDIM; kb += PBK) {
#pragma unroll
        for (int it = 0; it < 4; ++it) {
            int idx = it * 256 + tid;
            int kq = idx & 7, ml = idx >> 3;
            int m = by * PBM + ml;
            int b = m & 63, tl = m >> 6;
            const float* arow = x + ((size_t)b * TSTEPS + (size_t)(t0 + tl)) * INDIM;
            float4 v = *(const float4*)(arow + kb + kq * 4);
            As[kq * 4 + 0][ml] = v.x; As[kq * 4 + 1][ml] = v.y;
            As[kq * 4 + 2][ml] = v.z; As[kq * 4 + 3][ml] = v.w;
        }
#pragma unroll
        for (int it = 0; it < 2; ++it) {
            int idx = it * 256 + tid;
            int kq = idx & 7, nl = idx >> 3;
            int n = bx * PBN + nl;
            const float* brow = (n < N_E) ? (We + (size_t)n * INDIM)
                                          : (Wi + (size_t)(n - N_E) * INDIM);
            float4 v = *(const float4*)(brow + kb + kq * 4);
            Bs[kq * 4 + 0][nl] = v.x; Bs[kq * 4 + 1][nl] = v.y;
            Bs[kq * 4 + 2][nl] = v.z; Bs[kq * 4 + 3][nl] = v.w;
        }
        __syncthreads();
#pragma unroll
        for (int k = 0; k < PBK; ++k) {
            float4 a0 = *(const float4*)&As[k][ty * 8];
            float4 a1 = *(const float4*)&As[k][ty * 8 + 4];
            float4 b0 = *(const float4*)&Bs[k][tx * 4];
            float a[8] = {a0.x, a0.y, a0.z, a0.w, a1.x, a1.y, a1.z, a1.w};
            float bb[4] = {b0.x, b0.y, b0.z, b0.w};
#pragma unroll
            for (int i = 0; i < 8; ++i)
#pragma unroll
                for (int j = 0; j < 4; ++j)
                    acc[i][j] = fmaf(a[i], bb[j], acc[i][j]);
        }
        __syncthreads();
    }
#pragma unroll
    for (int i = 0; i < 8; ++i) {
        int m = by * PBM + ty * 8 + i;
        f32x4 o = { acc[i][0], acc[i][1], acc[i][2], acc[i][3] };
        __builtin_nontemporal_store(o, (f32x4*)(out + (size_t)m * N_TOT + bx * PBN + tx * 4));
    }
}

__device__ __forceinline__ float inline_proj(const float* __restrict__ x,
                                             const float* __restrict__ We_in,
                                             const float* __restrict__ Wi_in,
                                             int b, int t, int n)
{
    const float* xr = x + ((size_t)b * TSTEPS + (size_t)t) * INDIM;
    const float* wr = (n < N_E) ? (We_in + (size_t)n * INDIM)
                                : (Wi_in + (size_t)(n - N_E) * INDIM);
    float a = 0.f;
#pragma unroll
    for (int k = 0; k < INDIM; k += 4) {
        float4 w = *(const float4*)(wr + k);
        float4 xv = *(const float4*)(xr + k);
        a = fmaf(w.x, xv.x, a); a = fmaf(w.y, xv.y, a);
        a = fmaf(w.z, xv.z, a); a = fmaf(w.w, xv.w, a);
    }
    return a;
}

// ------------------------------------------------------------------
// PULL sim with COMPRESSED gather: per spike, thread t reads one
// bitmap u32 + one cum u16 (phase 1, independent), then <=4 predicated
// value loads (phase 2). ~3 cache lines/spike/wave vs 80 dense.
// Table is 3.3 MB -> L2-resident. Zero atomics; 2 barriers/step.
// ------------------------------------------------------------------
__global__ __launch_bounds__(640) void sim_kernel(
    const float* __restrict__ i_inp,
    const float* __restrict__ x, const float* __restrict__ We_in, const float* __restrict__ Wi_in,
    const char* __restrict__ sp,
    float* __restrict__ gv, float* __restrict__ gi, unsigned* __restrict__ g_cnt,
    int* __restrict__ g_list, int* __restrict__ g_nspk,
    int t0, int tc, int first)
{
    __shared__ int list_s[2][N_TOT];
    __shared__ int nspk_s[2];

    int b = blockIdx.x, tid = threadIdx.x, lane = tid & 63;
    int p0 = tid * 4;
    bool isE = (tid < 512);
    float tm = isE ? 0.05f : 0.1f;
    int word = tid >> 3;               // bitmap word index for posts 4t..4t+3
    int sh = (tid & 7) * 4;            // nibble shift within the word

    float v0, v1, v2, v3, c0, c1, c2, c3;
    unsigned n0c = 0u, n1c = 0u, n2c = 0u, n3c = 0u;
    if (first) {
        v0 = v1 = v2 = v3 = 0.f; c0 = c1 = c2 = c3 = 0.f;
        if (tid == 0) nspk_s[0] = 0;
    } else {
        float4 vv = *(const float4*)(gv + (size_t)b * N_TOT + p0);
        float4 cc = *(const float4*)(gi + (size_t)b * N_TOT + p0);
        v0 = vv.x; v1 = vv.y; v2 = vv.z; v3 = vv.w;
        c0 = cc.x; c1 = cc.y; c2 = cc.z; c3 = cc.w;
        if (isE) {
            uint4 q = *(const uint4*)(g_cnt + (size_t)b * N_E + p0);
            n0c = q.x; n1c = q.y; n2c = q.z; n3c = q.w;
        }
        if (tid == 0) nspk_s[0] = g_nspk[b];
    }
    __syncthreads();
    if (!first) {
        int n0 = nspk_s[0];
        for (int s = tid; s < n0; s += 640) list_s[0][s] = g_list[(size_t)b * N_TOT + s];
    }
    __syncthreads();

    f32x4 pf = { 0.f, 0.f, 0.f, 0.f };
    if (i_inp)
        pf = __builtin_nontemporal_load((const f32x4*)(i_inp + (size_t)b * N_TOT + p0));

    for (int tl = 0; tl < tc; ++tl) {
        int cur = tl & 1, nxt = cur ^ 1;
        if (tid == 0) nspk_s[nxt] = 0;

        float I0, I1, I2, I3;
        f32x4 pfn = { 0.f, 0.f, 0.f, 0.f };
        if (i_inp) {
            I0 = pf.x; I1 = pf.y; I2 = pf.z; I3 = pf.w;
            if (tl + 1 < tc)
                pfn = __builtin_nontemporal_load(
                    (const f32x4*)(i_inp + ((size_t)(tl + 1) * BATCH + b) * N_TOT + p0));
        } else {
            const float* xr = x + ((size_t)b * TSTEPS + (size_t)(t0 + tl)) * INDIM;
            const float* w0 = isE ? (We_in + (size_t)p0 * INDIM)
                                  : (Wi_in + (size_t)(p0 - N_E) * INDIM);
            I0 = I1 = I2 = I3 = 0.f;
            for (int k = 0; k < INDIM; ++k) {
                float xv = xr[k];
                I0 = fmaf(w0[k], xv, I0);
                I1 = fmaf(w0[INDIM + k], xv, I1);
                I2 = fmaf(w0[2 * INDIM + k], xv, I2);
                I3 = fmaf(w0[3 * INDIM + k], xv, I3);
            }
        }

        // gather: compressed rows. phase 1: bitmap+cum (independent loads);
        // phase 2: predicated value loads.
        int ns = nspk_s[cur];
        const int* lst = list_s[cur];
        for (int s0 = 0; s0 < ns; s0 += GD) {
            int take = ns - s0; if (take > GD) take = GD;
            unsigned off[GD]; unsigned bw[GD]; unsigned short cum[GD];
#pragma unroll
            for (int k = 0; k < GD; ++k) {
                if (k < take) {
                    off[k] = (unsigned)lst[s0 + k] * (unsigned)ROWB;
                    bw[k] = *(const unsigned*)(sp + off[k] + (size_t)word * 4);
                    cum[k] = *(const unsigned short*)(sp + off[k] + 320 + (size_t)word * 2);
                }
            }
#pragma unroll
            for (int k = 0; k < GD; ++k) {
                if (k < take) {
                    unsigned nib = (bw[k] >> sh) & 0xFu;
                    if (nib) {
                        int idx = (int)cum[k] + __popc(bw[k] & ((1u << sh) - 1u));
                        const unsigned short* vals =
                            (const unsigned short*)(sp + off[k] + 480);
                        if (nib & 1u)
                            I0 += __half2float(__ushort_as_half(vals[idx]));
                        if (nib & 2u)
                            I1 += __half2float(__ushort_as_half(vals[idx + __popc(nib & 1u)]));
                        if (nib & 4u)
                            I2 += __half2float(__ushort_as_half(vals[idx + __popc(nib & 3u)]));
                        if (nib & 8u)
                            I3 += __half2float(__ushort_as_half(vals[idx + __popc(nib & 7u)]));
                    }
                }
            }
        }

        // LIF in registers
        float vd0 = v0 + tm * (c0 - v0); bool z0 = vd0 > 1.0f; v0 = z0 ? 0.f : vd0; c0 = 0.8f * c0 + I0;
        float vd1 = v1 + tm * (c1 - v1); bool z1 = vd1 > 1.0f; v1 = z1 ? 0.f : vd1; c1 = 0.8f * c1 + I1;
        float vd2 = v2 + tm * (c2 - v2); bool z2 = vd2 > 1.0f; v2 = z2 ? 0.f : vd2; c2 = 0.8f * c2 + I2;
        float vd3 = v3 + tm * (c3 - v3); bool z3 = vd3 > 1.0f; v3 = z3 ? 0.f : vd3; c3 = 0.8f * c3 + I3;
        if (isE) { n0c += z0; n1c += z1; n2c += z2; n3c += z3; }

        __syncthreads();   // barrier 1: gathers of cur done; reset of nxt visible

        unsigned long long m0 = __ballot(z0), m1 = __ballot(z1);
        unsigned long long m2 = __ballot(z2), m3 = __ballot(z3);
        int w0c = __popcll(m0), w1c = __popcll(m1), w2c = __popcll(m2), w3c = __popcll(m3);
        int tot = w0c + w1c + w2c + w3c;
        if (tot) {
            int base = 0;
            if (lane == 0) base = atomicAdd(&nspk_s[nxt], tot);
            base = __shfl(base, 0);
            unsigned long long pre = (1ull << lane) - 1ull;
            if (z0) list_s[nxt][base + __popcll(m0 & pre)] = p0;
            if (z1) list_s[nxt][base + w0c + __popcll(m1 & pre)] = p0 + 1;
            if (z2) list_s[nxt][base + w0c + w1c + __popcll(m2 & pre)] = p0 + 2;
            if (z3) list_s[nxt][base + w0c + w1c + w2c + __popcll(m3 & pre)] = p0 + 3;
        }
        __syncthreads();   // barrier 2: appends complete
        pf = pfn;
    }

    *(float4*)(gv + (size_t)b * N_TOT + p0) = make_float4(v0, v1, v2, v3);
    *(float4*)(gi + (size_t)b * N_TOT + p0) = make_float4(c0, c1, c2, c3);
    if (isE) *(uint4*)(g_cnt + (size_t)b * N_E + p0) = make_uint4(n0c, n1c, n2c, n3c);
    int fin = tc & 1;
    if (tid == 0) g_nspk[b] = nspk_s[fin];
    for (int s = tid; s < nspk_s[fin]; s += 640) g_list[(size_t)b * N_TOT + s] = list_s[fin][s];
}

// ------------------------------------------------------------------
// Readout
// ------------------------------------------------------------------
__global__ __launch_bounds__(256) void readout_kernel(
    const unsigned* __restrict__ g_cnt,
    const float* __restrict__ rw, const float* __restrict__ rb, float* __restrict__ out)
{
    int b = blockIdx.x, tid = threadIdx.x;
    float a0 = 0.f, a1 = 0.f, a2 = 0.f;
    for (int n = tid; n < N_E; n += 256) {
        float c = (float)g_cnt[(size_t)b * N_E + n];
        a0 = fmaf(c, rw[n], a0);
        a1 = fmaf(c, rw[N_E + n], a1);
        a2 = fmaf(c, rw[2 * N_E + n], a2);
    }
#pragma unroll
    for (int off = 32; off > 0; off >>= 1) {
        a0 += __shfl_down(a0, off);
        a1 += __shfl_down(a1, off);
        a2 += __shfl_down(a2, off);
    }
    __shared__ float part[3][4];
    int wid = tid >> 6, lane = tid & 63;
    if (lane == 0) { part[0][wid] = a0; part[1][wid] = a1; part[2][wid] = a2; }
    __syncthreads();
    if (tid == 0) {
        float s0 = part[0][0] + part[0][1] + part[0][2] + part[0][3];
        float s1 = part[1][0] + part[1][1] + part[1][2] + part[1][3];
        float s2 = part[2][0] + part[2][1] + part[2][2] + part[2][3];
        const float inv = 1.0f / 512.0f;
        out[b * 3 + 0] = fmaf(s0, inv, rb[0]);
        out[b * 3 + 1] = fmaf(s1, inv, rb[1]);
        out[b * 3 + 2] = fmaf(s2, inv, rb[2]);
    }
}

// ------------------------------------------------------------------
extern "C" void kernel_launch(void* const* d_in, const int* in_sizes, int n_in,
                              void* d_out, int out_size, void* d_ws, size_t ws_size,
                              hipStream_t stream)
{
    const float* x     = (const float*)d_in[0];
    const float* Wee   = (const float*)d_in[1];
    const float* Wie   = (const float*)d_in[2];
    const float* Wei   = (const float*)d_in[3];
    const float* Wii   = (const float*)d_in[4];
    const float* We_in = (const float*)d_in[5];
    const float* Wi_in = (const float*)d_in[6];
    const float* rw    = (const float*)d_in[7];
    const float* rb    = (const float*)d_in[8];
    float* out = (float*)d_out;
    char* ws = (char*)d_ws;

    size_t off = 0;
    auto alloc = [&](size_t bytes) {
        size_t o = off;
        off = (off + bytes + 255) & ~(size_t)255;
        return o;
    };
    size_t o_wd    = alloc((size_t)N_TOT * N_TOT * 2);   // 13.1 MB dense fp16 (build source)
    size_t o_sp    = alloc((size_t)N_TOT * ROWB);        // 3.3 MB compressed table
    size_t o_gv    = alloc((size_t)BATCH * N_TOT * 4);
    size_t o_gi    = alloc((size_t)BATCH * N_TOT * 4);
    size_t o_gcnt  = alloc((size_t)BATCH * N_E * 4);
    size_t o_glist = alloc((size_t)BATCH * N_TOT * 4);
    size_t o_gnspk = alloc((size_t)BATCH * 4);
    size_t o_iinp  = off;   // remainder for the input-projection chunk

    int tc = 0;
    if (ws_size > o_iinp) {
        size_t avail = ws_size - o_iinp;
        tc = TSTEPS;
        while (tc >= 2 && (size_t)tc * BATCH * N_TOT * 4 > avail) tc >>= 1;
        if (tc < 2) tc = 0;
    }

    __half*   p_wd    = (__half*)(ws + o_wd);
    char*     p_sp    = ws + o_sp;
    float*    p_gv    = (float*)(ws + o_gv);
    float*    p_gi    = (float*)(ws + o_gi);
    unsigned* p_gcnt  = (unsigned*)(ws + o_gcnt);
    int*      p_glist = (int*)(ws + o_glist);
    int*      p_gnspk = (int*)(ws + o_gnspk);
    float*    p_iinp  = (float*)(ws + o_iinp);

    // ---- build dense table, then compress ----
    dim3 wg(N_TOT / TS, N_TOT / TS);
    build_wd_kernel<<<wg, 256, 0, stream>>>(Wee, Wie, Wei, Wii, p_wd);
    compress_kernel<<<N_TOT, 128, 0, stream>>>(p_wd, p_sp);

    // ---- time loop: proj GEMM chunk + persistent sim ----
    if (tc >= 2) {
        for (int t0 = 0; t0 < TSTEPS; t0 += tc) {
            dim3 pg(N_TOT / PBN, (tc * BATCH) / PBM);
            proj_kernel<<<pg, 256, 0, stream>>>(x, We_in, Wi_in, p_iinp, t0);
            sim_kernel<<<BATCH, 640, 0, stream>>>(
                p_iinp, x, We_in, Wi_in, p_sp,
                p_gv, p_gi, p_gcnt, p_glist, p_gnspk,
                t0, tc, (t0 == 0) ? 1 : 0);
        }
    } else {
        sim_kernel<<<BATCH, 640, 0, stream>>>(
            nullptr, x, We_in, Wi_in, p_sp,
            p_gv, p_gi, p_gcnt, p_glist, p_gnspk,
            0, TSTEPS, 1);
    }

    // ---- readout ----
    readout_kernel<<<BATCH, 256, 0, stream>>>(p_gcnt, rw, rb, out);
}

// Round 17
// 6415.305 us; speedup vs baseline: 1.4642x; 1.4642x over previous
//
#include <hip/hip_runtime.h>
#include <hip/hip_fp16.h>
#include <cstdint>
#include <cstddef>

#define N_E 2048
#define N_I 512
#define N_TOT 2560
#define BATCH 64
#define TSTEPS 512
#define INDIM 128
#define GD 12                 // gather batch depth

typedef float f32x4 __attribute__((ext_vector_type(4)));

// ------------------------------------------------------------------
// Dense signed-relu weight table Wd[pre][post] (fp16), tiled transpose.
// (build source for the compressed table)
// ------------------------------------------------------------------
#define TS 64
__global__ __launch_bounds__(256) void build_wd_kernel(
    const float* __restrict__ Wee, const float* __restrict__ Wie,
    const float* __restrict__ Wei, const float* __restrict__ Wii,
    __half* __restrict__ Wd)
{
    __shared__ float tile[TS][TS + 1];
    int P0 = blockIdx.x * TS;
    int Q0 = blockIdx.y * TS;
    int tx = threadIdx.x & 63, ty = threadIdx.x >> 6;

    const float* W; int ldw, po_off, pr_off; float sign;
    bool preE = (P0 < N_E), postE = (Q0 < N_E);
    if (postE && preE)        { W = Wee; ldw = N_E; po_off = 0;   pr_off = 0;   sign =  1.f; }
    else if (!postE && preE)  { W = Wie; ldw = N_E; po_off = N_E; pr_off = 0;   sign =  1.f; }
    else if (postE && !preE)  { W = Wei; ldw = N_I; po_off = 0;   pr_off = N_E; sign = -1.f; }
    else                      { W = Wii; ldw = N_I; po_off = N_E; pr_off = N_E; sign = -1.f; }

    for (int r = ty; r < TS; r += 4) {
        int post = Q0 + r, pre = P0 + tx;
        float v = W[(size_t)(post - po_off) * ldw + (pre - pr_off)];
        tile[r][tx] = (v > 0.f) ? sign * v : 0.f;
    }
    __syncthreads();
    for (int r = ty; r < TS; r += 4) {
        int pre = P0 + r, post = Q0 + tx;
        Wd[(size_t)pre * N_TOT + post] = __float2half(tile[tx][r]);
    }
}

// ------------------------------------------------------------------
// Compression: nnz per row -> row byte offsets -> meta+values rows.
// Row layout: meta u64[80] {lo32=bitmap, bits32..47=cum-exclusive} |
//             values fp16[nnz] | >=16B pad. 16B-aligned rows.
// ------------------------------------------------------------------
__global__ __launch_bounds__(128) void rowcnt_kernel(
    const __half* __restrict__ Wd, unsigned* __restrict__ rownnz)
{
    __shared__ unsigned cnt_s[80];
    int j = blockIdx.x, t = threadIdx.x;
    const unsigned short* row = (const unsigned short*)(Wd + (size_t)j * N_TOT);
    if (t < 80) {
        int c = 0;
        for (int b = 0; b < 32; ++b)
            if (row[t * 32 + b] & 0x7FFF) ++c;
        cnt_s[t] = (unsigned)c;
    }
    __syncthreads();
    if (t == 0) {
        unsigned a = 0;
        for (int w = 0; w < 80; ++w) a += cnt_s[w];
        rownnz[j] = a;
    }
}

__global__ __launch_bounds__(256) void offscan_kernel(
    const unsigned* __restrict__ rownnz, unsigned* __restrict__ rowoff)
{
    __shared__ unsigned sums[256];
    int t = threadIdx.x;
    int base = t * 10;                   // 2560 = 256*10
    unsigned loc[10];
    unsigned s = 0;
    for (int i = 0; i < 10; ++i) {
        loc[i] = s;
        unsigned rb = 640u + 2u * rownnz[base + i] + 16u;
        rb = (rb + 15u) & ~15u;
        s += rb;
    }
    sums[t] = s;
    __syncthreads();
    if (t == 0) {
        unsigned a = 0;
        for (int i = 0; i < 256; ++i) { unsigned v = sums[i]; sums[i] = a; a += v; }
    }
    __syncthreads();
    unsigned offt = sums[t];
    for (int i = 0; i < 10; ++i) rowoff[base + i] = offt + loc[i];
}

__global__ __launch_bounds__(128) void compress_kernel(
    const __half* __restrict__ Wd, const unsigned* __restrict__ rowoff,
    char* __restrict__ sp)
{
    __shared__ unsigned short cnt_s[80];
    __shared__ unsigned short cum_s[80];
    __shared__ unsigned mask_s[80];
    int j = blockIdx.x, t = threadIdx.x;
    const unsigned short* row = (const unsigned short*)(Wd + (size_t)j * N_TOT);
    if (t < 80) {
        unsigned m = 0; int c = 0;
        for (int b = 0; b < 32; ++b) {
            unsigned short h = row[t * 32 + b];
            if (h & 0x7FFF) { m |= (1u << b); ++c; }
        }
        mask_s[t] = m; cnt_s[t] = (unsigned short)c;
    }
    __syncthreads();
    if (t == 0) {
        unsigned a = 0;
        for (int w = 0; w < 80; ++w) { cum_s[w] = (unsigned short)a; a += cnt_s[w]; }
    }
    __syncthreads();
    char* rb = sp + rowoff[j];
    if (t < 80) {
        ((unsigned long long*)rb)[t] =
            (unsigned long long)mask_s[t] | ((unsigned long long)cum_s[t] << 32);
        unsigned short* vals = (unsigned short*)(rb + 640);
        int o = cum_s[t];
        unsigned m = mask_s[t];
        for (int b = 0; b < 32; ++b)
            if ((m >> b) & 1u) vals[o++] = row[t * 32 + b];
    }
}

// ------------------------------------------------------------------
// Input projection GEMM (nt store of the single-use stream).
// ------------------------------------------------------------------
#define PBM 128
#define PBN 64
#define PBK 32
__global__ __launch_bounds__(256) void proj_kernel(
    const float* __restrict__ x, const float* __restrict__ We, const float* __restrict__ Wi,
    float* __restrict__ out, int t0)
{
    __shared__ __align__(16) float As[PBK][132];
    __shared__ __align__(16) float Bs[PBK][68];
    int tid = threadIdx.x;
    int bx = blockIdx.x, by = blockIdx.y;
    int tx = tid & 15, ty = tid >> 4;
    float acc[8][4];
#pragma unroll
    for (int i = 0; i < 8; ++i)
#pragma unroll
        for (int j = 0; j < 4; ++j) acc[i][j] = 0.0f;

    for (int kb = 0; kb < INDIM; kb += PBK) {
#pragma unroll
        for (int it = 0; it < 4; ++it) {
            int idx = it * 256 + tid;
            int kq = idx & 7, ml = idx >> 3;
            int m = by * PBM + ml;
            int b = m & 63, tl = m >> 6;
            const float* arow = x + ((size_t)b * TSTEPS + (size_t)(t0 + tl)) * INDIM;
            float4 v = *(const float4*)(arow + kb + kq * 4);
            As[kq * 4 + 0][ml] = v.x; As[kq * 4 + 1][ml] = v.y;
            As[kq * 4 + 2][ml] = v.z; As[kq * 4 + 3][ml] = v.w;
        }
#pragma unroll
        for (int it = 0; it < 2; ++it) {
            int idx = it * 256 + tid;
            int kq = idx & 7, nl = idx >> 3;
            int n = bx * PBN + nl;
            const float* brow = (n < N_E) ? (We + (size_t)n * INDIM)
                                          : (Wi + (size_t)(n - N_E) * INDIM);
            float4 v = *(const float4*)(brow + kb + kq * 4);
            Bs[kq * 4 + 0][nl] = v.x; Bs[kq * 4 + 1][nl] = v.y;
            Bs[kq * 4 + 2][nl] = v.z; Bs[kq * 4 + 3][nl] = v.w;
        }
        __syncthreads();
#pragma unroll
        for (int k = 0; k < PBK; ++k) {
            float4 a0 = *(const float4*)&As[k][ty * 8];
            float4 a1 = *(const float4*)&As[k][ty * 8 + 4];
            float4 b0 = *(const float4*)&Bs[k][tx * 4];
            float a[8] = {a0.x, a0.y, a0.z, a0.w, a1.x, a1.y, a1.z, a1.w};
            float bb[4] = {b0.x, b0.y, b0.z, b0.w};
#pragma unroll
            for (int i = 0; i < 8; ++i)
#pragma unroll
                for (int j = 0; j < 4; ++j)
                    acc[i][j] = fmaf(a[i], bb[j], acc[i][j]);
        }
        __syncthreads();
    }
#pragma unroll
    for (int i = 0; i < 8; ++i) {
        int m = by * PBM + ty * 8 + i;
        f32x4 o = { acc[i][0], acc[i][1], acc[i][2], acc[i][3] };
        __builtin_nontemporal_store(o, (f32x4*)(out + (size_t)m * N_TOT + bx * PBN + tx * 4));
    }
}

__device__ __forceinline__ float inline_proj(const float* __restrict__ x,
                                             const float* __restrict__ We_in,
                                             const float* __restrict__ Wi_in,
                                             int b, int t, int n)
{
    const float* xr = x + ((size_t)b * TSTEPS + (size_t)t) * INDIM;
    const float* wr = (n < N_E) ? (We_in + (size_t)n * INDIM)
                                : (Wi_in + (size_t)(n - N_E) * INDIM);
    float a = 0.f;
#pragma unroll
    for (int k = 0; k < INDIM; k += 4) {
        float4 w = *(const float4*)(wr + k);
        float4 xv = *(const float4*)(xr + k);
        a = fmaf(w.x, xv.x, a); a = fmaf(w.y, xv.y, a);
        a = fmaf(w.z, xv.z, a); a = fmaf(w.w, xv.w, a);
    }
    return a;
}

// ------------------------------------------------------------------
// PULL sim, compressed 2-load gather:
//   per spike per wave: 1 u64 meta load + 1 predicated 12B value load.
//   Branchless value select; row offsets cached in LDS.
// ------------------------------------------------------------------
__global__ __launch_bounds__(640) void sim_kernel(
    const float* __restrict__ i_inp,
    const float* __restrict__ x, const float* __restrict__ We_in, const float* __restrict__ Wi_in,
    const char* __restrict__ sp, const unsigned* __restrict__ rowoff,
    float* __restrict__ gv, float* __restrict__ gi, unsigned* __restrict__ g_cnt,
    int* __restrict__ g_list, int* __restrict__ g_nspk,
    int t0, int tc, int first)
{
    __shared__ int list_s[2][N_TOT];
    __shared__ unsigned offtab[N_TOT];
    __shared__ int nspk_s[2];

    int b = blockIdx.x, tid = threadIdx.x, lane = tid & 63;
    int p0 = tid * 4;
    bool isE = (tid < 512);
    float tm = isE ? 0.05f : 0.1f;
    int word = tid >> 3;               // meta u64 index for posts 4t..4t+3
    int sh = (tid & 7) * 4;            // nibble shift within the bitmap word

    for (int n = tid; n < N_TOT; n += 640) offtab[n] = rowoff[n];

    float v0, v1, v2, v3, c0, c1, c2, c3;
    unsigned n0c = 0u, n1c = 0u, n2c = 0u, n3c = 0u;
    if (first) {
        v0 = v1 = v2 = v3 = 0.f; c0 = c1 = c2 = c3 = 0.f;
        if (tid == 0) nspk_s[0] = 0;
    } else {
        float4 vv = *(const float4*)(gv + (size_t)b * N_TOT + p0);
        float4 cc = *(const float4*)(gi + (size_t)b * N_TOT + p0);
        v0 = vv.x; v1 = vv.y; v2 = vv.z; v3 = vv.w;
        c0 = cc.x; c1 = cc.y; c2 = cc.z; c3 = cc.w;
        if (isE) {
            uint4 q = *(const uint4*)(g_cnt + (size_t)b * N_E + p0);
            n0c = q.x; n1c = q.y; n2c = q.z; n3c = q.w;
        }
        if (tid == 0) nspk_s[0] = g_nspk[b];
    }
    __syncthreads();
    if (!first) {
        int n0 = nspk_s[0];
        for (int s = tid; s < n0; s += 640) list_s[0][s] = g_list[(size_t)b * N_TOT + s];
    }
    __syncthreads();

    f32x4 pf = { 0.f, 0.f, 0.f, 0.f };
    if (i_inp)
        pf = __builtin_nontemporal_load((const f32x4*)(i_inp + (size_t)b * N_TOT + p0));

    for (int tl = 0; tl < tc; ++tl) {
        int cur = tl & 1, nxt = cur ^ 1;
        if (tid == 0) nspk_s[nxt] = 0;

        float I0, I1, I2, I3;
        f32x4 pfn = { 0.f, 0.f, 0.f, 0.f };
        if (i_inp) {
            I0 = pf.x; I1 = pf.y; I2 = pf.z; I3 = pf.w;
            if (tl + 1 < tc)
                pfn = __builtin_nontemporal_load(
                    (const f32x4*)(i_inp + ((size_t)(tl + 1) * BATCH + b) * N_TOT + p0));
        } else {
            const float* xr = x + ((size_t)b * TSTEPS + (size_t)(t0 + tl)) * INDIM;
            const float* w0 = isE ? (We_in + (size_t)p0 * INDIM)
                                  : (Wi_in + (size_t)(p0 - N_E) * INDIM);
            I0 = I1 = I2 = I3 = 0.f;
            for (int k = 0; k < INDIM; ++k) {
                float xv = xr[k];
                I0 = fmaf(w0[k], xv, I0);
                I1 = fmaf(w0[INDIM + k], xv, I1);
                I2 = fmaf(w0[2 * INDIM + k], xv, I2);
                I3 = fmaf(w0[3 * INDIM + k], xv, I3);
            }
        }

        // gather: per spike 1 meta load + 1 predicated 12B value load
        int ns = nspk_s[cur];
        const int* lst = list_s[cur];
        for (int s0 = 0; s0 < ns; s0 += GD) {
            int take = ns - s0; if (take > GD) take = GD;
            unsigned long long meta[GD]; unsigned off[GD];
#pragma unroll
            for (int k = 0; k < GD; ++k) {
                if (k < take) {
                    int j = lst[s0 + k];
                    off[k] = offtab[j];
                    meta[k] = *(const unsigned long long*)(sp + off[k] + (size_t)word * 8);
                }
            }
#pragma unroll
            for (int k = 0; k < GD; ++k) {
                if (k < take) {
                    unsigned bw = (unsigned)meta[k];
                    unsigned nib = (bw >> sh) & 0xFu;
                    unsigned cum = (unsigned)(meta[k] >> 32) & 0xFFFFu;
                    unsigned idx = cum + (unsigned)__popc(bw & ((1u << sh) - 1u));
                    uint3 w = make_uint3(0u, 0u, 0u);
                    if (nib)
                        w = *(const uint3*)(sp + off[k] + 640 + ((size_t)(idx & ~1u) << 1));
                    int a = idx & 1;
                    // branchless select of half q from the 6 loaded halfs
                    auto pick = [&](int q) -> float {
                        unsigned w32 = (q < 2) ? w.x : ((q < 4) ? w.y : w.z);
                        unsigned short us = (q & 1) ? (unsigned short)(w32 >> 16)
                                                    : (unsigned short)(w32 & 0xFFFFu);
                        return __half2float(__ushort_as_half(us));
                    };
                    I0 += (nib & 1u) ? pick(a) : 0.f;
                    I1 += (nib & 2u) ? pick(a + __popc(nib & 1u)) : 0.f;
                    I2 += (nib & 4u) ? pick(a + __popc(nib & 3u)) : 0.f;
                    I3 += (nib & 8u) ? pick(a + __popc(nib & 7u)) : 0.f;
                }
            }
        }

        // LIF in registers
        float vd0 = v0 + tm * (c0 - v0); bool z0 = vd0 > 1.0f; v0 = z0 ? 0.f : vd0; c0 = 0.8f * c0 + I0;
        float vd1 = v1 + tm * (c1 - v1); bool z1 = vd1 > 1.0f; v1 = z1 ? 0.f : vd1; c1 = 0.8f * c1 + I1;
        float vd2 = v2 + tm * (c2 - v2); bool z2 = vd2 > 1.0f; v2 = z2 ? 0.f : vd2; c2 = 0.8f * c2 + I2;
        float vd3 = v3 + tm * (c3 - v3); bool z3 = vd3 > 1.0f; v3 = z3 ? 0.f : vd3; c3 = 0.8f * c3 + I3;
        if (isE) { n0c += z0; n1c += z1; n2c += z2; n3c += z3; }

        __syncthreads();   // barrier 1

        unsigned long long m0 = __ballot(z0), m1 = __ballot(z1);
        unsigned long long m2 = __ballot(z2), m3 = __ballot(z3);
        int w0c = __popcll(m0), w1c = __popcll(m1), w2c = __popcll(m2), w3c = __popcll(m3);
        int tot = w0c + w1c + w2c + w3c;
        if (tot) {
            int base = 0;
            if (lane == 0) base = atomicAdd(&nspk_s[nxt], tot);
            base = __shfl(base, 0);
            unsigned long long pre = (1ull << lane) - 1ull;
            if (z0) list_s[nxt][base + __popcll(m0 & pre)] = p0;
            if (z1) list_s[nxt][base + w0c + __popcll(m1 & pre)] = p0 + 1;
            if (z2) list_s[nxt][base + w0c + w1c + __popcll(m2 & pre)] = p0 + 2;
            if (z3) list_s[nxt][base + w0c + w1c + w2c + __popcll(m3 & pre)] = p0 + 3;
        }
        __syncthreads();   // barrier 2
        pf = pfn;
    }

    *(float4*)(gv + (size_t)b * N_TOT + p0) = make_float4(v0, v1, v2, v3);
    *(float4*)(gi + (size_t)b * N_TOT + p0) = make_float4(c0, c1, c2, c3);
    if (isE) *(uint4*)(g_cnt + (size_t)b * N_E + p0) = make_uint4(n0c, n1c, n2c, n3c);
    int fin = tc & 1;
    if (tid == 0) g_nspk[b] = nspk_s[fin];
    for (int s = tid; s < nspk_s[fin]; s += 640) g_list[(size_t)b * N_TOT + s] = list_s[fin][s];
}

// ------------------------------------------------------------------
// Readout
// ------------------------------------------------------------------
__global__ __launch_bounds__(256) void readout_kernel(
    const unsigned* __restrict__ g_cnt,
    const float* __restrict__ rw, const float* __restrict__ rb, float* __restrict__ out)
{
    int b = blockIdx.x, tid = threadIdx.x;
    float a0 = 0.f, a1 = 0.f, a2 = 0.f;
    for (int n = tid; n < N_E; n += 256) {
        float c = (float)g_cnt[(size_t)b * N_E + n];
        a0 = fmaf(c, rw[n], a0);
        a1 = fmaf(c, rw[N_E + n], a1);
        a2 = fmaf(c, rw[2 * N_E + n], a2);
    }
#pragma unroll
    for (int off = 32; off > 0; off >>= 1) {
        a0 += __shfl_down(a0, off);
        a1 += __shfl_down(a1, off);
        a2 += __shfl_down(a2, off);
    }
    __shared__ float part[3][4];
    int wid = tid >> 6, lane = tid & 63;
    if (lane == 0) { part[0][wid] = a0; part[1][wid] = a1; part[2][wid] = a2; }
    __syncthreads();
    if (tid == 0) {
        float s0 = part[0][0] + part[0][1] + part[0][2] + part[0][3];
        float s1 = part[1][0] + part[1][1] + part[1][2] + part[1][3];
        float s2 = part[2][0] + part[2][1] + part[2][2] + part[2][3];
        const float inv = 1.0f / 512.0f;
        out[b * 3 + 0] = fmaf(s0, inv, rb[0]);
        out[b * 3 + 1] = fmaf(s1, inv, rb[1]);
        out[b * 3 + 2] = fmaf(s2, inv, rb[2]);
    }
}

// ------------------------------------------------------------------
extern "C" void kernel_launch(void* const* d_in, const int* in_sizes, int n_in,
                              void* d_out, int out_size, void* d_ws, size_t ws_size,
                              hipStream_t stream)
{
    const float* x     = (const float*)d_in[0];
    const float* Wee   = (const float*)d_in[1];
    const float* Wie   = (const float*)d_in[2];
    const float* Wei   = (const float*)d_in[3];
    const float* Wii   = (const float*)d_in[4];
    const float* We_in = (const float*)d_in[5];
    const float* Wi_in = (const float*)d_in[6];
    const float* rw    = (const float*)d_in[7];
    const float* rb    = (const float*)d_in[8];
    float* out = (float*)d_out;
    char* ws = (char*)d_ws;

    size_t off = 0;
    auto alloc = [&](size_t bytes) {
        size_t o = off;
        off = (off + bytes + 255) & ~(size_t)255;
        return o;
    };
    size_t o_wd    = alloc((size_t)N_TOT * N_TOT * 2);   // 13.1 MB dense (build source)
    size_t o_sp    = alloc((size_t)6 * 1024 * 1024);     // compressed table (~2.3 MB used)
    size_t o_nnz   = alloc((size_t)N_TOT * 4);
    size_t o_roff  = alloc((size_t)N_TOT * 4);
    size_t o_gv    = alloc((size_t)BATCH * N_TOT * 4);
    size_t o_gi    = alloc((size_t)BATCH * N_TOT * 4);
    size_t o_gcnt  = alloc((size_t)BATCH * N_E * 4);
    size_t o_glist = alloc((size_t)BATCH * N_TOT * 4);
    size_t o_gnspk = alloc((size_t)BATCH * 4);
    size_t o_iinp  = off;

    int tc = 0;
    if (ws_size > o_iinp) {
        size_t avail = ws_size - o_iinp;
        tc = TSTEPS;
        while (tc >= 2 && (size_t)tc * BATCH * N_TOT * 4 > avail) tc >>= 1;
        if (tc < 2) tc = 0;
    }

    __half*   p_wd    = (__half*)(ws + o_wd);
    char*     p_sp    = ws + o_sp;
    unsigned* p_nnz   = (unsigned*)(ws + o_nnz);
    unsigned* p_roff  = (unsigned*)(ws + o_roff);
    float*    p_gv    = (float*)(ws + o_gv);
    float*    p_gi    = (float*)(ws + o_gi);
    unsigned* p_gcnt  = (unsigned*)(ws + o_gcnt);
    int*      p_glist = (int*)(ws + o_glist);
    int*      p_gnspk = (int*)(ws + o_gnspk);
    float*    p_iinp  = (float*)(ws + o_iinp);

    // ---- build dense table, then compress ----
    dim3 wg(N_TOT / TS, N_TOT / TS);
    build_wd_kernel<<<wg, 256, 0, stream>>>(Wee, Wie, Wei, Wii, p_wd);
    rowcnt_kernel<<<N_TOT, 128, 0, stream>>>(p_wd, p_nnz);
    offscan_kernel<<<1, 256, 0, stream>>>(p_nnz, p_roff);
    compress_kernel<<<N_TOT, 128, 0, stream>>>(p_wd, p_roff, p_sp);

    // ---- time loop: proj GEMM chunk + persistent sim ----
    if (tc >= 2) {
        for (int t0 = 0; t0 < TSTEPS; t0 += tc) {
            dim3 pg(N_TOT / PBN, (tc * BATCH) / PBM);
            proj_kernel<<<pg, 256, 0, stream>>>(x, We_in, Wi_in, p_iinp, t0);
            sim_kernel<<<BATCH, 640, 0, stream>>>(
                p_iinp, x, We_in, Wi_in, p_sp, p_roff,
                p_gv, p_gi, p_gcnt, p_glist, p_gnspk,
                t0, tc, (t0 == 0) ? 1 : 0);
        }
    } else {
        sim_kernel<<<BATCH, 640, 0, stream>>>(
            nullptr, x, We_in, Wi_in, p_sp, p_roff,
            p_gv, p_gi, p_gcnt, p_glist, p_gnspk,
            0, TSTEPS, 1);
    }

    // ---- readout ----
    readout_kernel<<<BATCH, 256, 0, stream>>>(p_gcnt, rw, rb, out);
}

// Round 18
// 4267.320 us; speedup vs baseline: 2.2012x; 1.5034x over previous
//
#include <hip/hip_runtime.h>
#include <hip/hip_fp16.h>
#include <cstdint>
#include <cstddef>

#define N_E 2048
#define N_I 512
#define N_TOT 2560
#define BATCH 64
#define TSTEPS 512
#define INDIM 128
#define GD 32                 // gather batch depth (one memory round-trip for ns<=32)

// ------------------------------------------------------------------
// Dense signed-relu weight table Wd[pre][post] (fp16), tiled transpose.
// ------------------------------------------------------------------
#define TS 64
__global__ __launch_bounds__(256) void build_wd_kernel(
    const float* __restrict__ Wee, const float* __restrict__ Wie,
    const float* __restrict__ Wei, const float* __restrict__ Wii,
    __half* __restrict__ Wd)
{
    __shared__ float tile[TS][TS + 1];
    int P0 = blockIdx.x * TS;   // pre base
    int Q0 = blockIdx.y * TS;   // post base
    int tx = threadIdx.x & 63, ty = threadIdx.x >> 6;

    const float* W; int ldw, po_off, pr_off; float sign;
    bool preE = (P0 < N_E), postE = (Q0 < N_E);
    if (postE && preE)        { W = Wee; ldw = N_E; po_off = 0;   pr_off = 0;   sign =  1.f; }
    else if (!postE && preE)  { W = Wie; ldw = N_E; po_off = N_E; pr_off = 0;   sign =  1.f; }
    else if (postE && !preE)  { W = Wei; ldw = N_I; po_off = 0;   pr_off = N_E; sign = -1.f; }
    else                      { W = Wii; ldw = N_I; po_off = N_E; pr_off = N_E; sign = -1.f; }

    for (int r = ty; r < TS; r += 4) {
        int post = Q0 + r, pre = P0 + tx;
        float v = W[(size_t)(post - po_off) * ldw + (pre - pr_off)];
        tile[r][tx] = (v > 0.f) ? sign * v : 0.f;
    }
    __syncthreads();
    for (int r = ty; r < TS; r += 4) {
        int pre = P0 + r, post = Q0 + tx;
        Wd[(size_t)pre * N_TOT + post] = __float2half(tile[tx][r]);
    }
}

// ------------------------------------------------------------------
// Input projection GEMM (r12 version, plain stores)
// ------------------------------------------------------------------
#define PBM 128
#define PBN 64
#define PBK 32
__global__ __launch_bounds__(256) void proj_kernel(
    const float* __restrict__ x, const float* __restrict__ We, const float* __restrict__ Wi,
    float* __restrict__ out, int t0)
{
    __shared__ __align__(16) float As[PBK][132];
    __shared__ __align__(16) float Bs[PBK][68];
    int tid = threadIdx.x;
    int bx = blockIdx.x, by = blockIdx.y;
    int tx = tid & 15, ty = tid >> 4;
    float acc[8][4];
#pragma unroll
    for (int i = 0; i < 8; ++i)
#pragma unroll
        for (int j = 0; j < 4; ++j) acc[i][j] = 0.0f;

    for (int kb = 0; kb < INDIM; kb += PBK) {
#pragma unroll
        for (int it = 0; it < 4; ++it) {
            int idx = it * 256 + tid;
            int kq = idx & 7, ml = idx >> 3;
            int m = by * PBM + ml;
            int b = m & 63, tl = m >> 6;
            const float* arow = x + ((size_t)b * TSTEPS + (size_t)(t0 + tl)) * INDIM;
            float4 v = *(const float4*)(arow + kb + kq * 4);
            As[kq * 4 + 0][ml] = v.x; As[kq * 4 + 1][ml] = v.y;
            As[kq * 4 + 2][ml] = v.z; As[kq * 4 + 3][ml] = v.w;
        }
#pragma unroll
        for (int it = 0; it < 2; ++it) {
            int idx = it * 256 + tid;
            int kq = idx & 7, nl = idx >> 3;
            int n = bx * PBN + nl;
            const float* brow = (n < N_E) ? (We + (size_t)n * INDIM)
                                          : (Wi + (size_t)(n - N_E) * INDIM);
            float4 v = *(const float4*)(brow + kb + kq * 4);
            Bs[kq * 4 + 0][nl] = v.x; Bs[kq * 4 + 1][nl] = v.y;
            Bs[kq * 4 + 2][nl] = v.z; Bs[kq * 4 + 3][nl] = v.w;
        }
        __syncthreads();
#pragma unroll
        for (int k = 0; k < PBK; ++k) {
            float4 a0 = *(const float4*)&As[k][ty * 8];
            float4 a1 = *(const float4*)&As[k][ty * 8 + 4];
            float4 b0 = *(const float4*)&Bs[k][tx * 4];
            float a[8] = {a0.x, a0.y, a0.z, a0.w, a1.x, a1.y, a1.z, a1.w};
            float bb[4] = {b0.x, b0.y, b0.z, b0.w};
#pragma unroll
            for (int i = 0; i < 8; ++i)
#pragma unroll
                for (int j = 0; j < 4; ++j)
                    acc[i][j] = fmaf(a[i], bb[j], acc[i][j]);
        }
        __syncthreads();
    }
#pragma unroll
    for (int i = 0; i < 8; ++i) {
        int m = by * PBM + ty * 8 + i;
        float4 o = make_float4(acc[i][0], acc[i][1], acc[i][2], acc[i][3]);
        *(float4*)(out + (size_t)m * N_TOT + bx * PBN + tx * 4) = o;
    }
}

__device__ __forceinline__ float inline_proj(const float* __restrict__ x,
                                             const float* __restrict__ We_in,
                                             const float* __restrict__ Wi_in,
                                             int b, int t, int n)
{
    const float* xr = x + ((size_t)b * TSTEPS + (size_t)t) * INDIM;
    const float* wr = (n < N_E) ? (We_in + (size_t)n * INDIM)
                                : (Wi_in + (size_t)(n - N_E) * INDIM);
    float a = 0.f;
#pragma unroll
    for (int k = 0; k < INDIM; k += 4) {
        float4 w = *(const float4*)(wr + k);
        float4 xv = *(const float4*)(xr + k);
        a = fmaf(w.x, xv.x, a); a = fmaf(w.y, xv.y, a);
        a = fmaf(w.z, xv.z, a); a = fmaf(w.w, xv.w, a);
    }
    return a;
}

// ------------------------------------------------------------------
// PULL sim, r12 structure but ONE barrier per step via 3-phase
// spike-list rotation: step t reads list[t%3], appends list[(t+1)%3],
// resets count[(t+2)%3]. Every same-buffer write/read pair is
// separated by >=1 barrier.
// ------------------------------------------------------------------
__global__ __launch_bounds__(640) void sim_kernel(
    const float* __restrict__ i_inp,
    const float* __restrict__ x, const float* __restrict__ We_in, const float* __restrict__ Wi_in,
    const __half* __restrict__ Wd,
    float* __restrict__ gv, float* __restrict__ gi, unsigned* __restrict__ g_cnt,
    int* __restrict__ g_list, int* __restrict__ g_nspk,
    int t0, int tc, int first)
{
    __shared__ int list_s[3][N_TOT];
    __shared__ int nspk_s[3];

    int b = blockIdx.x, tid = threadIdx.x, lane = tid & 63;
    int p0 = tid * 4;
    bool isE = (tid < 512);
    float tm = isE ? 0.05f : 0.1f;

    float v0, v1, v2, v3, c0, c1, c2, c3;
    unsigned n0c = 0u, n1c = 0u, n2c = 0u, n3c = 0u;
    if (first) {
        v0 = v1 = v2 = v3 = 0.f; c0 = c1 = c2 = c3 = 0.f;
        if (tid == 0) { nspk_s[0] = 0; nspk_s[1] = 0; nspk_s[2] = 0; }
    } else {
        float4 vv = *(const float4*)(gv + (size_t)b * N_TOT + p0);
        float4 cc = *(const float4*)(gi + (size_t)b * N_TOT + p0);
        v0 = vv.x; v1 = vv.y; v2 = vv.z; v3 = vv.w;
        c0 = cc.x; c1 = cc.y; c2 = cc.z; c3 = cc.w;
        if (isE) {
            uint4 q = *(const uint4*)(g_cnt + (size_t)b * N_E + p0);
            n0c = q.x; n1c = q.y; n2c = q.z; n3c = q.w;
        }
        if (tid == 0) { nspk_s[0] = g_nspk[b]; nspk_s[1] = 0; nspk_s[2] = 0; }
    }
    __syncthreads();
    if (!first) {
        int n0 = nspk_s[0];
        for (int s = tid; s < n0; s += 640) list_s[0][s] = g_list[(size_t)b * N_TOT + s];
    }
    __syncthreads();

    const unsigned short* Wdu = (const unsigned short*)Wd;

    float4 pf = make_float4(0.f, 0.f, 0.f, 0.f);
    if (i_inp) pf = *(const float4*)(i_inp + (size_t)b * N_TOT + p0);

    int cur = 0;
    for (int tl = 0; tl < tc; ++tl) {
        int nxt = cur + 1; if (nxt == 3) nxt = 0;
        int rst = nxt + 1; if (rst == 3) rst = 0;
        if (tid == 0) nspk_s[rst] = 0;   // consumed at step tl-1; appended at tl+1

        float I0, I1, I2, I3;
        float4 pfn = make_float4(0.f, 0.f, 0.f, 0.f);
        if (i_inp) {
            I0 = pf.x; I1 = pf.y; I2 = pf.z; I3 = pf.w;
            if (tl + 1 < tc)
                pfn = *(const float4*)(i_inp + ((size_t)(tl + 1) * BATCH + b) * N_TOT + p0);
        } else {
            const float* xr = x + ((size_t)b * TSTEPS + (size_t)(t0 + tl)) * INDIM;
            const float* w0 = isE ? (We_in + (size_t)p0 * INDIM)
                                  : (Wi_in + (size_t)(p0 - N_E) * INDIM);
            I0 = I1 = I2 = I3 = 0.f;
            for (int k = 0; k < INDIM; ++k) {
                float xv = xr[k];
                I0 = fmaf(w0[k], xv, I0);
                I1 = fmaf(w0[INDIM + k], xv, I1);
                I2 = fmaf(w0[2 * INDIM + k], xv, I2);
                I3 = fmaf(w0[3 * INDIM + k], xv, I3);
            }
        }

        // gather: batched predicated loads, all issued before any use
        int ns = nspk_s[cur];
        const int* lst = list_s[cur];
        for (int s0 = 0; s0 < ns; s0 += GD) {
            int take = ns - s0; if (take > GD) take = GD;
            ushort4 w[GD];
#pragma unroll
            for (int k = 0; k < GD; ++k) {
                if (k < take) {
                    int j = lst[s0 + k];
                    w[k] = *(const ushort4*)(Wdu + (size_t)j * N_TOT + p0);
                }
            }
#pragma unroll
            for (int k = 0; k < GD; ++k) {
                if (k < take) {
                    I0 += __half2float(__ushort_as_half(w[k].x));
                    I1 += __half2float(__ushort_as_half(w[k].y));
                    I2 += __half2float(__ushort_as_half(w[k].z));
                    I3 += __half2float(__ushort_as_half(w[k].w));
                }
            }
        }

        // LIF in registers
        float vd0 = v0 + tm * (c0 - v0); bool z0 = vd0 > 1.0f; v0 = z0 ? 0.f : vd0; c0 = 0.8f * c0 + I0;
        float vd1 = v1 + tm * (c1 - v1); bool z1 = vd1 > 1.0f; v1 = z1 ? 0.f : vd1; c1 = 0.8f * c1 + I1;
        float vd2 = v2 + tm * (c2 - v2); bool z2 = vd2 > 1.0f; v2 = z2 ? 0.f : vd2; c2 = 0.8f * c2 + I2;
        float vd3 = v3 + tm * (c3 - v3); bool z3 = vd3 > 1.0f; v3 = z3 ? 0.f : vd3; c3 = 0.8f * c3 + I3;
        if (isE) { n0c += z0; n1c += z1; n2c += z2; n3c += z3; }

        // aggregated spike append into list[nxt] (appends at tl; reads at tl+1
        // are across the barrier below; reset of nxt happened at tl-1)
        unsigned long long m0 = __ballot(z0), m1 = __ballot(z1);
        unsigned long long m2 = __ballot(z2), m3 = __ballot(z3);
        int w0c = __popcll(m0), w1c = __popcll(m1), w2c = __popcll(m2), w3c = __popcll(m3);
        int tot = w0c + w1c + w2c + w3c;
        if (tot) {
            int base = 0;
            if (lane == 0) base = atomicAdd(&nspk_s[nxt], tot);
            base = __shfl(base, 0);
            unsigned long long pre = (1ull << lane) - 1ull;
            if (z0) list_s[nxt][base + __popcll(m0 & pre)] = p0;
            if (z1) list_s[nxt][base + w0c + __popcll(m1 & pre)] = p0 + 1;
            if (z2) list_s[nxt][base + w0c + w1c + __popcll(m2 & pre)] = p0 + 2;
            if (z3) list_s[nxt][base + w0c + w1c + w2c + __popcll(m3 & pre)] = p0 + 3;
        }
        __syncthreads();   // the ONLY barrier per step
        pf = pfn;
        cur = nxt;
    }

    *(float4*)(gv + (size_t)b * N_TOT + p0) = make_float4(v0, v1, v2, v3);
    *(float4*)(gi + (size_t)b * N_TOT + p0) = make_float4(c0, c1, c2, c3);
    if (isE) *(uint4*)(g_cnt + (size_t)b * N_E + p0) = make_uint4(n0c, n1c, n2c, n3c);
    // pending spikes live in buffer cur (== tc % 3)
    if (tid == 0) g_nspk[b] = nspk_s[cur];
    for (int s = tid; s < nspk_s[cur]; s += 640) g_list[(size_t)b * N_TOT + s] = list_s[cur][s];
}

// ------------------------------------------------------------------
// Readout
// ------------------------------------------------------------------
__global__ __launch_bounds__(256) void readout_kernel(
    const unsigned* __restrict__ g_cnt,
    const float* __restrict__ rw, const float* __restrict__ rb, float* __restrict__ out)
{
    int b = blockIdx.x, tid = threadIdx.x;
    float a0 = 0.f, a1 = 0.f, a2 = 0.f;
    for (int n = tid; n < N_E; n += 256) {
        float c = (float)g_cnt[(size_t)b * N_E + n];
        a0 = fmaf(c, rw[n], a0);
        a1 = fmaf(c, rw[N_E + n], a1);
        a2 = fmaf(c, rw[2 * N_E + n], a2);
    }
#pragma unroll
    for (int off = 32; off > 0; off >>= 1) {
        a0 += __shfl_down(a0, off);
        a1 += __shfl_down(a1, off);
        a2 += __shfl_down(a2, off);
    }
    __shared__ float part[3][4];
    int wid = tid >> 6, lane = tid & 63;
    if (lane == 0) { part[0][wid] = a0; part[1][wid] = a1; part[2][wid] = a2; }
    __syncthreads();
    if (tid == 0) {
        float s0 = part[0][0] + part[0][1] + part[0][2] + part[0][3];
        float s1 = part[1][0] + part[1][1] + part[1][2] + part[1][3];
        float s2 = part[2][0] + part[2][1] + part[2][2] + part[2][3];
        const float inv = 1.0f / 512.0f;
        out[b * 3 + 0] = fmaf(s0, inv, rb[0]);
        out[b * 3 + 1] = fmaf(s1, inv, rb[1]);
        out[b * 3 + 2] = fmaf(s2, inv, rb[2]);
    }
}

// ------------------------------------------------------------------
extern "C" void kernel_launch(void* const* d_in, const int* in_sizes, int n_in,
                              void* d_out, int out_size, void* d_ws, size_t ws_size,
                              hipStream_t stream)
{
    const float* x     = (const float*)d_in[0];
    const float* Wee   = (const float*)d_in[1];
    const float* Wie   = (const float*)d_in[2];
    const float* Wei   = (const float*)d_in[3];
    const float* Wii   = (const float*)d_in[4];
    const float* We_in = (const float*)d_in[5];
    const float* Wi_in = (const float*)d_in[6];
    const float* rw    = (const float*)d_in[7];
    const float* rb    = (const float*)d_in[8];
    float* out = (float*)d_out;
    char* ws = (char*)d_ws;

    size_t off = 0;
    auto alloc = [&](size_t bytes) {
        size_t o = off;
        off = (off + bytes + 255) & ~(size_t)255;
        return o;
    };
    size_t o_wd    = alloc((size_t)N_TOT * N_TOT * 2);        // 13.1 MB dense fp16
    size_t o_gv    = alloc((size_t)BATCH * N_TOT * 4);
    size_t o_gi    = alloc((size_t)BATCH * N_TOT * 4);
    size_t o_gcnt  = alloc((size_t)BATCH * N_E * 4);
    size_t o_glist = alloc((size_t)BATCH * N_TOT * 4);
    size_t o_gnspk = alloc((size_t)BATCH * 4);
    size_t o_iinp  = off;   // remainder for the input-projection chunk

    int tc = 0;
    if (ws_size > o_iinp) {
        size_t avail = ws_size - o_iinp;
        tc = TSTEPS;
        while (tc >= 2 && (size_t)tc * BATCH * N_TOT * 4 > avail) tc >>= 1;
        if (tc < 2) tc = 0;
    }

    __half*   p_wd    = (__half*)(ws + o_wd);
    float*    p_gv    = (float*)(ws + o_gv);
    float*    p_gi    = (float*)(ws + o_gi);
    unsigned* p_gcnt  = (unsigned*)(ws + o_gcnt);
    int*      p_glist = (int*)(ws + o_glist);
    int*      p_gnspk = (int*)(ws + o_gnspk);
    float*    p_iinp  = (float*)(ws + o_iinp);

    // ---- build dense signed-relu fp16 table ----
    dim3 wg(N_TOT / TS, N_TOT / TS);
    build_wd_kernel<<<wg, 256, 0, stream>>>(Wee, Wie, Wei, Wii, p_wd);

    // ---- time loop: proj GEMM chunk + persistent sim ----
    if (tc >= 2) {
        for (int t0 = 0; t0 < TSTEPS; t0 += tc) {
            dim3 pg(N_TOT / PBN, (tc * BATCH) / PBM);
            proj_kernel<<<pg, 256, 0, stream>>>(x, We_in, Wi_in, p_iinp, t0);
            sim_kernel<<<BATCH, 640, 0, stream>>>(
                p_iinp, x, We_in, Wi_in, p_wd,
                p_gv, p_gi, p_gcnt, p_glist, p_gnspk,
                t0, tc, (t0 == 0) ? 1 : 0);
        }
    } else {
        sim_kernel<<<BATCH, 640, 0, stream>>>(
            nullptr, x, We_in, Wi_in, p_wd,
            p_gv, p_gi, p_gcnt, p_glist, p_gnspk,
            0, TSTEPS, 1);
    }

    // ---- readout ----
    readout_kernel<<<BATCH, 256, 0, stream>>>(p_gcnt, rw, rb, out);
}